// Round 11
// baseline (187.630 us; speedup 1.0000x reference)
//
#include <hip/hip_runtime.h>
#include <math.h>

#define N_NODES 20000
#define N_EDGES 320000
#define IN_CH   256
#define HID_CH  256
#define OUT_CH  128
#define CAP     64     // per-node slot capacity; P(deg>64)~1e-15 for 320k->20k uniform

typedef __attribute__((ext_vector_type(8))) short short8;
typedef __attribute__((ext_vector_type(8))) unsigned short ushort8;
typedef __attribute__((ext_vector_type(4))) unsigned short ushort4v;
typedef __attribute__((ext_vector_type(4))) float floatx4;
typedef __attribute__((ext_vector_type(4))) _Float16 half4;

// bf16 round-to-nearest-even helpers
static __device__ __forceinline__ unsigned short f2bf(float f) {
    unsigned int u = __float_as_uint(f);
    u += 0x7FFFu + ((u >> 16) & 1u);
    return (unsigned short)(u >> 16);
}
static __device__ __forceinline__ float bf2f(unsigned short h) {
    return __uint_as_float(((unsigned int)h) << 16);
}

// ---------------------------------------------------------------------------
// init: zero deg + transpose/decompose both weights (line-contiguous writes)
// ---------------------------------------------------------------------------
__global__ __launch_bounds__(256)
void init_kernel(const float* __restrict__ W1, const float* __restrict__ W2,
                 unsigned short* __restrict__ W1thi, unsigned short* __restrict__ W1tlo,
                 unsigned short* __restrict__ W2thi, unsigned short* __restrict__ W2tlo,
                 int* __restrict__ deg) {
    const int g = blockIdx.x * blockDim.x + threadIdx.x;
    const int gsz = gridDim.x * blockDim.x;
    for (int i = g; i < N_NODES; i += gsz) deg[i] = 0;
    for (int t = g; t < (IN_CH * HID_CH) / 16; t += gsz) {
        int n = t >> 4;
        int kc = (t & 15) * 16;
        ushort8 h0, l0, h1, l1;
#pragma unroll
        for (int j = 0; j < 8; ++j) {
            float x = W1[(size_t)(kc + j) * HID_CH + n];
            h0[j] = f2bf(x); l0[j] = f2bf(x - bf2f(h0[j]));
            float y = W1[(size_t)(kc + 8 + j) * HID_CH + n];
            h1[j] = f2bf(y); l1[j] = f2bf(y - bf2f(h1[j]));
        }
        *(ushort8*)(W1thi + (size_t)n * IN_CH + kc)     = h0;
        *(ushort8*)(W1thi + (size_t)n * IN_CH + kc + 8) = h1;
        *(ushort8*)(W1tlo + (size_t)n * IN_CH + kc)     = l0;
        *(ushort8*)(W1tlo + (size_t)n * IN_CH + kc + 8) = l1;
    }
    for (int t = g; t < (HID_CH * OUT_CH) / 16; t += gsz) {
        int n = t >> 4;
        int kc = (t & 15) * 16;
        ushort8 h0, l0, h1, l1;
#pragma unroll
        for (int j = 0; j < 8; ++j) {
            float x = W2[(size_t)(kc + j) * OUT_CH + n];
            h0[j] = f2bf(x); l0[j] = f2bf(x - bf2f(h0[j]));
            float y = W2[(size_t)(kc + 8 + j) * OUT_CH + n];
            h1[j] = f2bf(y); l1[j] = f2bf(y - bf2f(h1[j]));
        }
        *(ushort8*)(W2thi + (size_t)n * HID_CH + kc)     = h0;
        *(ushort8*)(W2thi + (size_t)n * HID_CH + kc + 8) = h1;
        *(ushort8*)(W2tlo + (size_t)n * HID_CH + kc)     = l0;
        *(ushort8*)(W2tlo + (size_t)n * HID_CH + kc + 8) = l1;
    }
}

// ---------------------------------------------------------------------------
// slot-CSR build in ONE pass: deg count + bucket fill. srcs ushort, 128 B/node.
// ---------------------------------------------------------------------------
__global__ void degfill_kernel(const int* __restrict__ row, const int* __restrict__ col,
                               int* __restrict__ deg, unsigned short* __restrict__ srcs, int E) {
    int i = blockIdx.x * blockDim.x + threadIdx.x;
    if (i < E) {
        int c = col[i];
        int r = row[i];
        int p = atomicAdd(&deg[c], 1);
        srcs[(size_t)c * CAP + p] = (unsigned short)r;
    }
}

// ---------------------------------------------------------------------------
// GEMM1: split-bf16 MFMA, A = fp32 doc_embeds (hi/lo split in-register while
// staging), epilogue scales by dinv[m] = rsqrt(deg[m]+1), stores fp16.
// 64x128 tile, BK=32, 4 waves (2x2), 2x4 16x16x32 MFMA tiles/wave.
// 3-term compensation: hi*hi + hi*lo + lo*hi.
// ---------------------------------------------------------------------------
#define GK 256
__global__ __launch_bounds__(256)
void gemm1_kernel(const float* __restrict__ Afp,
                  const unsigned short* __restrict__ Bthi, const unsigned short* __restrict__ Btlo,
                  const int* __restrict__ deg, _Float16* __restrict__ C, int M, int N) {
    __shared__ unsigned short As[2][64][36];
    __shared__ unsigned short Bs[2][128][36];
    const int tid = threadIdx.x;
    const int m0 = blockIdx.y * 64;
    const int n0 = blockIdx.x * 128;
    const int lane = tid & 63;
    const int wave = tid >> 6;
    const int wr = (wave >> 1) * 32;
    const int wc = (wave & 1) * 64;
    const int lm = lane & 15;
    const int lk = (lane >> 4) * 8;

    floatx4 acc[2][4];
#pragma unroll
    for (int i = 0; i < 2; ++i)
#pragma unroll
        for (int j = 0; j < 4; ++j) acc[i][j] = (floatx4){0.f, 0.f, 0.f, 0.f};

    for (int k0 = 0; k0 < GK; k0 += 32) {
        {
            int r = tid >> 2;
            int ko = (tid & 3) * 8;
            ushort8 vh = {}, vl = {};
            if (m0 + r < M) {
                const float* ap = Afp + (size_t)(m0 + r) * GK + k0 + ko;
                float4 f0 = *(const float4*)ap;
                float4 f1 = *(const float4*)(ap + 4);
                float xs[8] = {f0.x, f0.y, f0.z, f0.w, f1.x, f1.y, f1.z, f1.w};
#pragma unroll
                for (int j = 0; j < 8; ++j) {
                    vh[j] = f2bf(xs[j]);
                    vl[j] = f2bf(xs[j] - bf2f(vh[j]));
                }
            }
            *(ushort8*)&As[0][r][ko] = vh;
            *(ushort8*)&As[1][r][ko] = vl;
        }
#pragma unroll
        for (int c = 0; c < 2; ++c) {
            int ch = tid + c * 256;
            int r = ch >> 2;
            int ko = (ch & 3) * 8;
            size_t gb = (size_t)(n0 + r) * GK + k0 + ko;
            *(ushort8*)&Bs[0][r][ko] = *(const ushort8*)(Bthi + gb);
            *(ushort8*)&Bs[1][r][ko] = *(const ushort8*)(Btlo + gb);
        }
        __syncthreads();

        short8 ah[2], al[2], bh[4], bl[4];
#pragma unroll
        for (int i = 0; i < 2; ++i) {
            ah[i] = *(const short8*)&As[0][wr + i * 16 + lm][lk];
            al[i] = *(const short8*)&As[1][wr + i * 16 + lm][lk];
        }
#pragma unroll
        for (int j = 0; j < 4; ++j) {
            bh[j] = *(const short8*)&Bs[0][wc + j * 16 + lm][lk];
            bl[j] = *(const short8*)&Bs[1][wc + j * 16 + lm][lk];
        }
#pragma unroll
        for (int i = 0; i < 2; ++i)
#pragma unroll
            for (int j = 0; j < 4; ++j) {
                acc[i][j] = __builtin_amdgcn_mfma_f32_16x16x32_bf16(ah[i], bh[j], acc[i][j], 0, 0, 0);
                acc[i][j] = __builtin_amdgcn_mfma_f32_16x16x32_bf16(ah[i], bl[j], acc[i][j], 0, 0, 0);
                acc[i][j] = __builtin_amdgcn_mfma_f32_16x16x32_bf16(al[i], bh[j], acc[i][j], 0, 0, 0);
            }
        __syncthreads();
    }

#pragma unroll
    for (int i = 0; i < 2; ++i) {
#pragma unroll
        for (int r = 0; r < 4; ++r) {
            int rowi = m0 + wr + i * 16 + (lane >> 4) * 4 + r;
            if (rowi < M) {
                float dr = 1.0f / sqrtf((float)(deg[rowi] + 1));
#pragma unroll
                for (int j = 0; j < 4; ++j) {
                    C[(size_t)rowi * N + n0 + wc + j * 16 + lm] = (_Float16)(dr * acc[i][j][r]);
                }
            }
        }
    }
}

// ---------------------------------------------------------------------------
// GEMM2 with FUSED layer-1 gather in A-staging:
//   H1[m,k] = relu( dc_m*(sum_{r in N(m)} X1s[r,k] + X1s[m,k]) + b1[k] )
//   X2s[m,n] = dinv[m] * (H1[m,:] . W2t[n,:])   (fp16 out)
// X1s rows are dinv[r]-prescaled by gemm1. H1 never materialized in memory.
// TM=32 (625 blocks, ~2.4/CU), BK=32; per k-iter each thread gathers 4
// channels of one row. K-loop sweeps 1.28 MB X1s k-slices -> L2-resident.
// ---------------------------------------------------------------------------
__global__ __launch_bounds__(256)
void gemm2_fused_kernel(const _Float16* __restrict__ X1, const int* __restrict__ deg,
                        const unsigned short* __restrict__ srcs, const float* __restrict__ b1,
                        const unsigned short* __restrict__ Bthi, const unsigned short* __restrict__ Btlo,
                        _Float16* __restrict__ C, int M, int N) {
    __shared__ unsigned short As[2][32][36];
    __shared__ unsigned short Bs[2][128][36];
    const int tid = threadIdx.x;
    const int m0 = blockIdx.x * 32;
    const int lane = tid & 63;
    const int wave = tid >> 6;
    const int wr = (wave >> 1) * 16;
    const int wc = (wave & 1) * 64;
    const int lm = lane & 15;
    const int lk = (lane >> 4) * 8;

    // gather identity: 8 threads per row, 4 channels each
    const int ar  = tid >> 3;          // row 0..31 in tile
    const int ako = (tid & 7) * 4;     // k offset 0,4,...,28
    const int m = m0 + ar;
    const int cnt  = (m < M) ? deg[m] : 0;
    const float dc = 1.0f / sqrtf((float)(cnt + 1));
    const size_t sbeg = (size_t)m * CAP;

    floatx4 acc[4];
#pragma unroll
    for (int j = 0; j < 4; ++j) acc[j] = (floatx4){0.f, 0.f, 0.f, 0.f};

    for (int k0 = 0; k0 < GK; k0 += 32) {
        // ---- fused A staging: gather + self + bias + relu + bf16 split ----
        {
            ushort4v vh = {}, vl = {};
            if (m < M) {
                const int kc = k0 + ako;
                float a0 = 0.f, a1 = 0.f, a2 = 0.f, a3 = 0.f;
                int e = 0;
                for (; e + 4 <= cnt; e += 4) {
                    ushort4v s4 = *(const ushort4v*)(srcs + sbeg + e);
                    half4 v0 = *(const half4*)(X1 + (size_t)s4.x * GK + kc);
                    half4 v1 = *(const half4*)(X1 + (size_t)s4.y * GK + kc);
                    half4 v2 = *(const half4*)(X1 + (size_t)s4.z * GK + kc);
                    half4 v3 = *(const half4*)(X1 + (size_t)s4.w * GK + kc);
                    a0 += (float)v0.x + (float)v1.x + (float)v2.x + (float)v3.x;
                    a1 += (float)v0.y + (float)v1.y + (float)v2.y + (float)v3.y;
                    a2 += (float)v0.z + (float)v1.z + (float)v2.z + (float)v3.z;
                    a3 += (float)v0.w + (float)v1.w + (float)v2.w + (float)v3.w;
                }
                for (; e < cnt; ++e) {
                    int r = srcs[sbeg + e];
                    half4 v = *(const half4*)(X1 + (size_t)r * GK + kc);
                    a0 += (float)v.x; a1 += (float)v.y;
                    a2 += (float)v.z; a3 += (float)v.w;
                }
                half4 self = *(const half4*)(X1 + (size_t)m * GK + kc);
                float4 bb = *(const float4*)(b1 + kc);
                float h0 = fmaxf(dc * (a0 + (float)self.x) + bb.x, 0.f);
                float h1 = fmaxf(dc * (a1 + (float)self.y) + bb.y, 0.f);
                float h2 = fmaxf(dc * (a2 + (float)self.z) + bb.z, 0.f);
                float h3 = fmaxf(dc * (a3 + (float)self.w) + bb.w, 0.f);
                vh.x = f2bf(h0); vl.x = f2bf(h0 - bf2f(vh.x));
                vh.y = f2bf(h1); vl.y = f2bf(h1 - bf2f(vh.y));
                vh.z = f2bf(h2); vl.z = f2bf(h2 - bf2f(vh.z));
                vh.w = f2bf(h3); vl.w = f2bf(h3 - bf2f(vh.w));
            }
            *(ushort4v*)&As[0][ar][ako] = vh;
            *(ushort4v*)&As[1][ar][ako] = vl;
        }
        // ---- B staging: 128 rows x 32 k, hi+lo ----
#pragma unroll
        for (int c = 0; c < 2; ++c) {
            int ch = tid + c * 256;
            int r = ch >> 2;
            int ko = (ch & 3) * 8;
            size_t gb = (size_t)r * GK + k0 + ko;   // n0 = 0 (N=128 single tile)
            *(ushort8*)&Bs[0][r][ko] = *(const ushort8*)(Bthi + gb);
            *(ushort8*)&Bs[1][r][ko] = *(const ushort8*)(Btlo + gb);
        }
        __syncthreads();

        short8 ah, al, bh[4], bl[4];
        ah = *(const short8*)&As[0][wr + lm][lk];
        al = *(const short8*)&As[1][wr + lm][lk];
#pragma unroll
        for (int j = 0; j < 4; ++j) {
            bh[j] = *(const short8*)&Bs[0][wc + j * 16 + lm][lk];
            bl[j] = *(const short8*)&Bs[1][wc + j * 16 + lm][lk];
        }
#pragma unroll
        for (int j = 0; j < 4; ++j) {
            acc[j] = __builtin_amdgcn_mfma_f32_16x16x32_bf16(ah, bh[j], acc[j], 0, 0, 0);
            acc[j] = __builtin_amdgcn_mfma_f32_16x16x32_bf16(ah, bl[j], acc[j], 0, 0, 0);
            acc[j] = __builtin_amdgcn_mfma_f32_16x16x32_bf16(al, bh[j], acc[j], 0, 0, 0);
        }
        __syncthreads();
    }

    // epilogue: scale by dinv[row], store fp16
#pragma unroll
    for (int r = 0; r < 4; ++r) {
        int rowi = m0 + wr + (lane >> 4) * 4 + r;
        if (rowi < M) {
            float dr = 1.0f / sqrtf((float)(deg[rowi] + 1));
#pragma unroll
            for (int j = 0; j < 4; ++j) {
                C[(size_t)rowi * N + wc + j * 16 + lm] = (_Float16)(dr * acc[j][r]);
            }
        }
    }
}

// ---------------------------------------------------------------------------
// XCD-sliced gather over ushort slot-CSR, fp16 X table. Slice = 32 ch =
// 8 lanes x half4. X rows dinv[src]-prescaled. NT fp32 store to final out.
// ---------------------------------------------------------------------------
template <int C, int NSLICE>
__global__ __launch_bounds__(256)
void gather_sliced_kernel(const _Float16* __restrict__ X, const int* __restrict__ deg,
                          const unsigned short* __restrict__ srcs,
                          const float* __restrict__ bias, float* __restrict__ outf, int n) {
    constexpr int SW = C / NSLICE;
    static_assert(SW == 32, "slice must be 32 channels");
    const int slice = blockIdx.x % NSLICE;
    const int ngrp  = blockIdx.x / NSLICE;
    const int wave = threadIdx.x >> 6;
    const int lane = threadIdx.x & 63;
    const int g  = lane >> 3;
    const int sl = lane & 7;
    const int node = ngrp * 32 + wave * 8 + g;
    if (node >= n) return;
    const int choff = slice * SW + sl * 4;
    const size_t beg = (size_t)node * CAP;
    const int cnt = deg[node];

    float4 acc = make_float4(0.f, 0.f, 0.f, 0.f);
    int e = 0;
    for (; e + 4 <= cnt; e += 4) {
        ushort4v s4 = *(const ushort4v*)(srcs + beg + e);
        half4 v0 = *(const half4*)(X + (size_t)s4.x * C + choff);
        half4 v1 = *(const half4*)(X + (size_t)s4.y * C + choff);
        half4 v2 = *(const half4*)(X + (size_t)s4.z * C + choff);
        half4 v3 = *(const half4*)(X + (size_t)s4.w * C + choff);
        acc.x += (float)v0.x + (float)v1.x + (float)v2.x + (float)v3.x;
        acc.y += (float)v0.y + (float)v1.y + (float)v2.y + (float)v3.y;
        acc.z += (float)v0.z + (float)v1.z + (float)v2.z + (float)v3.z;
        acc.w += (float)v0.w + (float)v1.w + (float)v2.w + (float)v3.w;
    }
    for (; e < cnt; ++e) {
        int r = srcs[beg + e];
        half4 v = *(const half4*)(X + (size_t)r * C + choff);
        acc.x += (float)v.x; acc.y += (float)v.y;
        acc.z += (float)v.z; acc.w += (float)v.w;
    }

    const float dc = 1.0f / sqrtf((float)(cnt + 1));
    half4 vsh = *(const half4*)(X + (size_t)node * C + choff);
    float4 bb = *(const float4*)(bias + choff);

    floatx4 o;
    o.x = dc * (acc.x + (float)vsh.x) + bb.x;
    o.y = dc * (acc.y + (float)vsh.y) + bb.y;
    o.z = dc * (acc.z + (float)vsh.z) + bb.z;
    o.w = dc * (acc.w + (float)vsh.w) + bb.w;
    __builtin_nontemporal_store(o, (floatx4*)(outf + (size_t)node * C + choff));
}

// ---------------------------------------------------------------------------
extern "C" void kernel_launch(void* const* d_in, const int* in_sizes, int n_in,
                              void* d_out, int out_size, void* d_ws, size_t ws_size,
                              hipStream_t stream) {
    const float* doc_embeds = (const float*)d_in[0];   // [20000,256]
    const int*   edge_index = (const int*)d_in[1];     // [2,320000]
    const float* W1 = (const float*)d_in[2];           // [256,256]
    const float* b1 = (const float*)d_in[3];           // [256]
    const float* W2 = (const float*)d_in[4];           // [256,128]
    const float* b2 = (const float*)d_in[5];           // [128]
    float* out = (float*)d_out;                        // [20000,128]

    const int* row = edge_index;            // sources
    const int* col = edge_index + N_EDGES;  // destinations

    // ---------------- workspace layout (256B aligned) ----------------
    char* ws = (char*)d_ws;
    auto align_up = [](size_t x) { return (x + 255) / 256 * 256; };

    _Float16* X1s = (_Float16*)(ws);                              // gemm1 out fp16 (10.24 MB)
    _Float16* X2s = (_Float16*)(ws + align_up((size_t)N_NODES * HID_CH * 2));  // gemm2 out (5.12 MB)
    char* meta = (char*)(ws + align_up((size_t)N_NODES * HID_CH * 2)
                            + align_up((size_t)N_NODES * OUT_CH * 2));
    unsigned short* W1thi = (unsigned short*)(meta); meta += align_up((size_t)IN_CH * HID_CH * 2);
    unsigned short* W1tlo = (unsigned short*)(meta); meta += align_up((size_t)IN_CH * HID_CH * 2);
    unsigned short* W2thi = (unsigned short*)(meta); meta += align_up((size_t)HID_CH * OUT_CH * 2);
    unsigned short* W2tlo = (unsigned short*)(meta); meta += align_up((size_t)HID_CH * OUT_CH * 2);
    int*            deg   = (int*)(meta);            meta += align_up((size_t)N_NODES * 4);
    unsigned short* srcs  = (unsigned short*)(meta); // 20000*64*2 = 2.56 MB

    // ---------------- prep ----------------
    init_kernel<<<256, 256, 0, stream>>>(W1, W2, W1thi, W1tlo, W2thi, W2tlo, deg);
    degfill_kernel<<<(N_EDGES + 255) / 256, 256, 0, stream>>>(row, col, deg, srcs, N_EDGES);

    // ---------------- layer 1 GEMM ----------------
    {
        dim3 grid(HID_CH / 128, (N_NODES + 63) / 64);   // (2, 313)
        gemm1_kernel<<<grid, 256, 0, stream>>>(doc_embeds, W1thi, W1tlo, deg, X1s, N_NODES, HID_CH);
    }

    // ---------------- layer 1 gather fused into layer 2 GEMM ----------------
    gemm2_fused_kernel<<<(N_NODES + 31) / 32, 256, 0, stream>>>(
        X1s, deg, srcs, b1, W2thi, W2tlo, X2s, N_NODES, OUT_CH);

    // ---------------- layer 2 gather -> d_out ----------------
    gather_sliced_kernel<OUT_CH, 4><<<((N_NODES + 31) / 32) * 4, 256, 0, stream>>>(
        X2s, deg, srcs, b2, out, N_NODES);
}

// Round 12
// 174.880 us; speedup vs baseline: 1.0729x; 1.0729x over previous
//
#include <hip/hip_runtime.h>
#include <math.h>

#define N_NODES 20000
#define N_EDGES 320000
#define IN_CH   256
#define HID_CH  256
#define OUT_CH  128
#define CAP     64     // per-node slot capacity; P(deg>64)~1e-15 for 320k->20k uniform

typedef __attribute__((ext_vector_type(8))) short short8;
typedef __attribute__((ext_vector_type(8))) unsigned short ushort8;
typedef __attribute__((ext_vector_type(4))) unsigned short ushort4v;
typedef __attribute__((ext_vector_type(4))) float floatx4;
typedef __attribute__((ext_vector_type(4))) _Float16 half4;
typedef __attribute__((ext_vector_type(8))) _Float16 half8;

// bf16 round-to-nearest-even helpers
static __device__ __forceinline__ unsigned short f2bf(float f) {
    unsigned int u = __float_as_uint(f);
    u += 0x7FFFu + ((u >> 16) & 1u);
    return (unsigned short)(u >> 16);
}
static __device__ __forceinline__ float bf2f(unsigned short h) {
    return __uint_as_float(((unsigned int)h) << 16);
}

// ---------------------------------------------------------------------------
// init: zero deg + transpose/decompose both weights (line-contiguous writes)
// ---------------------------------------------------------------------------
__global__ __launch_bounds__(256)
void init_kernel(const float* __restrict__ W1, const float* __restrict__ W2,
                 unsigned short* __restrict__ W1thi, unsigned short* __restrict__ W1tlo,
                 unsigned short* __restrict__ W2thi, unsigned short* __restrict__ W2tlo,
                 int* __restrict__ deg) {
    const int g = blockIdx.x * blockDim.x + threadIdx.x;
    const int gsz = gridDim.x * blockDim.x;
    for (int i = g; i < N_NODES; i += gsz) deg[i] = 0;
    for (int t = g; t < (IN_CH * HID_CH) / 16; t += gsz) {
        int n = t >> 4;
        int kc = (t & 15) * 16;
        ushort8 h0, l0, h1, l1;
#pragma unroll
        for (int j = 0; j < 8; ++j) {
            float x = W1[(size_t)(kc + j) * HID_CH + n];
            h0[j] = f2bf(x); l0[j] = f2bf(x - bf2f(h0[j]));
            float y = W1[(size_t)(kc + 8 + j) * HID_CH + n];
            h1[j] = f2bf(y); l1[j] = f2bf(y - bf2f(h1[j]));
        }
        *(ushort8*)(W1thi + (size_t)n * IN_CH + kc)     = h0;
        *(ushort8*)(W1thi + (size_t)n * IN_CH + kc + 8) = h1;
        *(ushort8*)(W1tlo + (size_t)n * IN_CH + kc)     = l0;
        *(ushort8*)(W1tlo + (size_t)n * IN_CH + kc + 8) = l1;
    }
    for (int t = g; t < (HID_CH * OUT_CH) / 16; t += gsz) {
        int n = t >> 4;
        int kc = (t & 15) * 16;
        ushort8 h0, l0, h1, l1;
#pragma unroll
        for (int j = 0; j < 8; ++j) {
            float x = W2[(size_t)(kc + j) * OUT_CH + n];
            h0[j] = f2bf(x); l0[j] = f2bf(x - bf2f(h0[j]));
            float y = W2[(size_t)(kc + 8 + j) * OUT_CH + n];
            h1[j] = f2bf(y); l1[j] = f2bf(y - bf2f(h1[j]));
        }
        *(ushort8*)(W2thi + (size_t)n * HID_CH + kc)     = h0;
        *(ushort8*)(W2thi + (size_t)n * HID_CH + kc + 8) = h1;
        *(ushort8*)(W2tlo + (size_t)n * HID_CH + kc)     = l0;
        *(ushort8*)(W2tlo + (size_t)n * HID_CH + kc + 8) = l1;
    }
}

// ---------------------------------------------------------------------------
// slot-CSR build in ONE pass: deg count + bucket fill. srcs ushort, 128 B/node.
// ---------------------------------------------------------------------------
__global__ void degfill_kernel(const int* __restrict__ row, const int* __restrict__ col,
                               int* __restrict__ deg, unsigned short* __restrict__ srcs, int E) {
    int i = blockIdx.x * blockDim.x + threadIdx.x;
    if (i < E) {
        int c = col[i];
        int r = row[i];
        int p = atomicAdd(&deg[c], 1);
        srcs[(size_t)c * CAP + p] = (unsigned short)r;
    }
}

// ---------------------------------------------------------------------------
// split-bf16 MFMA GEMM, epilogue scales by dinv[m] = rsqrt(deg[m]+1), fp16 out.
// AMODE 1: A fp32 [M][K]; AMODE 2: A fp16 [M][K]. Either way A is split to
// bf16 hi/lo in-register while staging (fp16->bf16x2 is exact).
// TM x 128 tile, BK=32, 4 waves (2x2), (TM/32)x4 16x16x32 MFMA tiles/wave.
// 3-term compensation: hi*hi + hi*lo + lo*hi.
// ---------------------------------------------------------------------------
#define GK 256
template <int AMODE, int TM>
__global__ __launch_bounds__(256)
void gemm_mfma_kernel(const float* __restrict__ Afp, const _Float16* __restrict__ Ah,
                      const unsigned short* __restrict__ Bthi, const unsigned short* __restrict__ Btlo,
                      const int* __restrict__ deg, _Float16* __restrict__ C, int M, int N) {
    constexpr int MI = TM / 32;
    __shared__ unsigned short As[2][TM][36];
    __shared__ unsigned short Bs[2][128][36];
    const int tid = threadIdx.x;
    const int m0 = blockIdx.y * TM;
    const int n0 = blockIdx.x * 128;
    const int lane = tid & 63;
    const int wave = tid >> 6;
    const int wr = (wave >> 1) * (TM / 2);
    const int wc = (wave & 1) * 64;
    const int lm = lane & 15;
    const int lk = (lane >> 4) * 8;

    floatx4 acc[MI][4];
#pragma unroll
    for (int i = 0; i < MI; ++i)
#pragma unroll
        for (int j = 0; j < 4; ++j) acc[i][j] = (floatx4){0.f, 0.f, 0.f, 0.f};

    for (int k0 = 0; k0 < GK; k0 += 32) {
#pragma unroll
        for (int c = 0; c < TM / 64; ++c) {
            int ch = tid + c * 256;
            int r = ch >> 2;
            int ko = (ch & 3) * 8;
            ushort8 vh = {}, vl = {};
            if (m0 + r < M) {
                float xs[8];
                if (AMODE == 1) {
                    const float* ap = Afp + (size_t)(m0 + r) * GK + k0 + ko;
                    float4 f0 = *(const float4*)ap;
                    float4 f1 = *(const float4*)(ap + 4);
                    xs[0] = f0.x; xs[1] = f0.y; xs[2] = f0.z; xs[3] = f0.w;
                    xs[4] = f1.x; xs[5] = f1.y; xs[6] = f1.z; xs[7] = f1.w;
                } else {
                    half8 hv = *(const half8*)(Ah + (size_t)(m0 + r) * GK + k0 + ko);
#pragma unroll
                    for (int j = 0; j < 8; ++j) xs[j] = (float)hv[j];
                }
#pragma unroll
                for (int j = 0; j < 8; ++j) {
                    vh[j] = f2bf(xs[j]);
                    vl[j] = f2bf(xs[j] - bf2f(vh[j]));
                }
            }
            *(ushort8*)&As[0][r][ko] = vh;
            *(ushort8*)&As[1][r][ko] = vl;
        }
#pragma unroll
        for (int c = 0; c < 2; ++c) {
            int ch = tid + c * 256;
            int r = ch >> 2;
            int ko = (ch & 3) * 8;
            size_t gb = (size_t)(n0 + r) * GK + k0 + ko;
            *(ushort8*)&Bs[0][r][ko] = *(const ushort8*)(Bthi + gb);
            *(ushort8*)&Bs[1][r][ko] = *(const ushort8*)(Btlo + gb);
        }
        __syncthreads();

        short8 ah[MI], al[MI], bh[4], bl[4];
#pragma unroll
        for (int i = 0; i < MI; ++i) {
            ah[i] = *(const short8*)&As[0][wr + i * 16 + lm][lk];
            al[i] = *(const short8*)&As[1][wr + i * 16 + lm][lk];
        }
#pragma unroll
        for (int j = 0; j < 4; ++j) {
            bh[j] = *(const short8*)&Bs[0][wc + j * 16 + lm][lk];
            bl[j] = *(const short8*)&Bs[1][wc + j * 16 + lm][lk];
        }
#pragma unroll
        for (int i = 0; i < MI; ++i)
#pragma unroll
            for (int j = 0; j < 4; ++j) {
                acc[i][j] = __builtin_amdgcn_mfma_f32_16x16x32_bf16(ah[i], bh[j], acc[i][j], 0, 0, 0);
                acc[i][j] = __builtin_amdgcn_mfma_f32_16x16x32_bf16(ah[i], bl[j], acc[i][j], 0, 0, 0);
                acc[i][j] = __builtin_amdgcn_mfma_f32_16x16x32_bf16(al[i], bh[j], acc[i][j], 0, 0, 0);
            }
        __syncthreads();
    }

#pragma unroll
    for (int i = 0; i < MI; ++i) {
#pragma unroll
        for (int r = 0; r < 4; ++r) {
            int rowi = m0 + wr + i * 16 + (lane >> 4) * 4 + r;
            if (rowi < M) {
                float dr = 1.0f / sqrtf((float)(deg[rowi] + 1));
#pragma unroll
                for (int j = 0; j < 4; ++j) {
                    C[(size_t)rowi * N + n0 + wc + j * 16 + lm] = (_Float16)(dr * acc[i][j][r]);
                }
            }
        }
    }
}

// ---------------------------------------------------------------------------
// XCD-sliced gather over ushort slot-CSR, fp16 X table. Slice = 32 ch =
// 8 lanes x half4 (8 B). Per-XCD hot set: X-slice (1.28 MB) + srcs (2.56 MB)
// + deg (80 KB) ~ 4 MB L2. X rows dinv[src]-prescaled by GEMM epilogue.
// MODE 0: fp32 NT store to final out. MODE 1: relu + fp16 H1 (cached;
// exactly representable by gemm2's in-register bf16 hi/lo split).
// ---------------------------------------------------------------------------
template <int C, int NSLICE, int MODE>
__global__ __launch_bounds__(256)
void gather_sliced_kernel(const _Float16* __restrict__ X, const int* __restrict__ deg,
                          const unsigned short* __restrict__ srcs,
                          const float* __restrict__ bias, float* __restrict__ outf,
                          _Float16* __restrict__ outh, int n) {
    constexpr int SW = C / NSLICE;
    static_assert(SW == 32, "slice must be 32 channels");
    const int slice = blockIdx.x % NSLICE;
    const int ngrp  = blockIdx.x / NSLICE;
    const int wave = threadIdx.x >> 6;
    const int lane = threadIdx.x & 63;
    const int g  = lane >> 3;
    const int sl = lane & 7;
    const int node = ngrp * 32 + wave * 8 + g;
    if (node >= n) return;
    const int choff = slice * SW + sl * 4;
    const size_t beg = (size_t)node * CAP;
    const int cnt = deg[node];

    float4 acc = make_float4(0.f, 0.f, 0.f, 0.f);
    int e = 0;
    for (; e + 4 <= cnt; e += 4) {
        ushort4v s4 = *(const ushort4v*)(srcs + beg + e);
        half4 v0 = *(const half4*)(X + (size_t)s4.x * C + choff);
        half4 v1 = *(const half4*)(X + (size_t)s4.y * C + choff);
        half4 v2 = *(const half4*)(X + (size_t)s4.z * C + choff);
        half4 v3 = *(const half4*)(X + (size_t)s4.w * C + choff);
        acc.x += (float)v0.x + (float)v1.x + (float)v2.x + (float)v3.x;
        acc.y += (float)v0.y + (float)v1.y + (float)v2.y + (float)v3.y;
        acc.z += (float)v0.z + (float)v1.z + (float)v2.z + (float)v3.z;
        acc.w += (float)v0.w + (float)v1.w + (float)v2.w + (float)v3.w;
    }
    for (; e < cnt; ++e) {
        int r = srcs[beg + e];
        half4 v = *(const half4*)(X + (size_t)r * C + choff);
        acc.x += (float)v.x; acc.y += (float)v.y;
        acc.z += (float)v.z; acc.w += (float)v.w;
    }

    const float dc = 1.0f / sqrtf((float)(cnt + 1));
    half4 vsh = *(const half4*)(X + (size_t)node * C + choff);  // dinv[node]-prescaled
    float4 bb = *(const float4*)(bias + choff);

    float o0 = dc * (acc.x + (float)vsh.x) + bb.x;
    float o1 = dc * (acc.y + (float)vsh.y) + bb.y;
    float o2 = dc * (acc.z + (float)vsh.z) + bb.z;
    float o3 = dc * (acc.w + (float)vsh.w) + bb.w;

    if constexpr (MODE == 1) {
        half4 h;
        h.x = (_Float16)fmaxf(o0, 0.f);
        h.y = (_Float16)fmaxf(o1, 0.f);
        h.z = (_Float16)fmaxf(o2, 0.f);
        h.w = (_Float16)fmaxf(o3, 0.f);
        *(half4*)(outh + (size_t)node * C + choff) = h;   // cached: gemm2 reads next
    } else {
        floatx4 o = {o0, o1, o2, o3};
        __builtin_nontemporal_store(o, (floatx4*)(outf + (size_t)node * C + choff));
    }
}

// ---------------------------------------------------------------------------
extern "C" void kernel_launch(void* const* d_in, const int* in_sizes, int n_in,
                              void* d_out, int out_size, void* d_ws, size_t ws_size,
                              hipStream_t stream) {
    const float* doc_embeds = (const float*)d_in[0];   // [20000,256]
    const int*   edge_index = (const int*)d_in[1];     // [2,320000]
    const float* W1 = (const float*)d_in[2];           // [256,256]
    const float* b1 = (const float*)d_in[3];           // [256]
    const float* W2 = (const float*)d_in[4];           // [256,128]
    const float* b2 = (const float*)d_in[5];           // [128]
    float* out = (float*)d_out;                        // [20000,128]

    const int* row = edge_index;            // sources
    const int* col = edge_index + N_EDGES;  // destinations

    // ---------------- workspace layout (256B aligned) ----------------
    char* ws = (char*)d_ws;
    auto align_up = [](size_t x) { return (x + 255) / 256 * 256; };

    _Float16* X1s = (_Float16*)(ws);                              // gemm1 out fp16 (10.24 MB)
    _Float16* H1  = (_Float16*)(ws + align_up((size_t)N_NODES * HID_CH * 2));  // fp16 (10.24 MB)
    _Float16* X2s = X1s;                                          // gemm2 out reuses X1s (5.12 MB)
    char* meta = (char*)(ws + 2 * align_up((size_t)N_NODES * HID_CH * 2));
    unsigned short* W1thi = (unsigned short*)(meta); meta += align_up((size_t)IN_CH * HID_CH * 2);
    unsigned short* W1tlo = (unsigned short*)(meta); meta += align_up((size_t)IN_CH * HID_CH * 2);
    unsigned short* W2thi = (unsigned short*)(meta); meta += align_up((size_t)HID_CH * OUT_CH * 2);
    unsigned short* W2tlo = (unsigned short*)(meta); meta += align_up((size_t)HID_CH * OUT_CH * 2);
    int*            deg   = (int*)(meta);            meta += align_up((size_t)N_NODES * 4);
    unsigned short* srcs  = (unsigned short*)(meta); // 20000*64*2 = 2.56 MB

    // ---------------- prep: init (zero deg + weight planes), slot-CSR ----------------
    init_kernel<<<256, 256, 0, stream>>>(W1, W2, W1thi, W1tlo, W2thi, W2tlo, deg);
    degfill_kernel<<<(N_EDGES + 255) / 256, 256, 0, stream>>>(row, col, deg, srcs, N_EDGES);

    // ---------------- layer 1 ----------------
    {
        dim3 grid(HID_CH / 128, (N_NODES + 63) / 64);   // (2, 313)
        gemm_mfma_kernel<1, 64><<<grid, 256, 0, stream>>>(
            doc_embeds, nullptr, W1thi, W1tlo, deg, X1s, N_NODES, HID_CH);
    }
    gather_sliced_kernel<HID_CH, 8, 1><<<((N_NODES + 31) / 32) * 8, 256, 0, stream>>>(
        X1s, deg, srcs, b1, nullptr, H1, N_NODES);

    // ---------------- layer 2 ----------------
    {
        dim3 grid(OUT_CH / 128, (N_NODES + 63) / 64);   // (1, 313)
        gemm_mfma_kernel<2, 64><<<grid, 256, 0, stream>>>(
            nullptr, H1, W2thi, W2tlo, deg, X2s, N_NODES, OUT_CH);
    }
    gather_sliced_kernel<OUT_CH, 4, 0><<<((N_NODES + 31) / 32) * 4, 256, 0, stream>>>(
        X2s, deg, srcs, b2, out, nullptr, N_NODES);
}

// Round 13
// 173.406 us; speedup vs baseline: 1.0820x; 1.0085x over previous
//
#include <hip/hip_runtime.h>
#include <math.h>

#define N_NODES 20000
#define N_EDGES 320000
#define IN_CH   256
#define HID_CH  256
#define OUT_CH  128
#define CAP     64     // per-node slot capacity; P(deg>64)~1e-15 for 320k->20k uniform

typedef __attribute__((ext_vector_type(8))) short short8;
typedef __attribute__((ext_vector_type(8))) unsigned short ushort8;
typedef __attribute__((ext_vector_type(4))) unsigned short ushort4v;
typedef __attribute__((ext_vector_type(4))) float floatx4;
typedef __attribute__((ext_vector_type(2))) float floatx2;
typedef __attribute__((ext_vector_type(4))) _Float16 half4;
typedef __attribute__((ext_vector_type(2))) _Float16 half2v;
typedef __attribute__((ext_vector_type(8))) _Float16 half8;

// bf16 round-to-nearest-even helpers
static __device__ __forceinline__ unsigned short f2bf(float f) {
    unsigned int u = __float_as_uint(f);
    u += 0x7FFFu + ((u >> 16) & 1u);
    return (unsigned short)(u >> 16);
}
static __device__ __forceinline__ float bf2f(unsigned short h) {
    return __uint_as_float(((unsigned int)h) << 16);
}

// ---------------------------------------------------------------------------
// fused prep: weight transpose/decompose (line-contiguous) + slot-CSR degfill.
// deg must be zeroed beforehand (hipMemsetAsync). Both parts are independent
// grid-stride loops -> overlap inside one dispatch.
// ---------------------------------------------------------------------------
__global__ __launch_bounds__(256)
void prep_kernel(const float* __restrict__ W1, const float* __restrict__ W2,
                 unsigned short* __restrict__ W1thi, unsigned short* __restrict__ W1tlo,
                 unsigned short* __restrict__ W2thi, unsigned short* __restrict__ W2tlo,
                 const int* __restrict__ row, const int* __restrict__ col,
                 int* __restrict__ deg, unsigned short* __restrict__ srcs) {
    const int g = blockIdx.x * blockDim.x + threadIdx.x;
    const int gsz = gridDim.x * blockDim.x;
    // weight planes
    for (int t = g; t < (IN_CH * HID_CH) / 16; t += gsz) {
        int n = t >> 4;
        int kc = (t & 15) * 16;
        ushort8 h0, l0, h1, l1;
#pragma unroll
        for (int j = 0; j < 8; ++j) {
            float x = W1[(size_t)(kc + j) * HID_CH + n];
            h0[j] = f2bf(x); l0[j] = f2bf(x - bf2f(h0[j]));
            float y = W1[(size_t)(kc + 8 + j) * HID_CH + n];
            h1[j] = f2bf(y); l1[j] = f2bf(y - bf2f(h1[j]));
        }
        *(ushort8*)(W1thi + (size_t)n * IN_CH + kc)     = h0;
        *(ushort8*)(W1thi + (size_t)n * IN_CH + kc + 8) = h1;
        *(ushort8*)(W1tlo + (size_t)n * IN_CH + kc)     = l0;
        *(ushort8*)(W1tlo + (size_t)n * IN_CH + kc + 8) = l1;
    }
    for (int t = g; t < (HID_CH * OUT_CH) / 16; t += gsz) {
        int n = t >> 4;
        int kc = (t & 15) * 16;
        ushort8 h0, l0, h1, l1;
#pragma unroll
        for (int j = 0; j < 8; ++j) {
            float x = W2[(size_t)(kc + j) * OUT_CH + n];
            h0[j] = f2bf(x); l0[j] = f2bf(x - bf2f(h0[j]));
            float y = W2[(size_t)(kc + 8 + j) * OUT_CH + n];
            h1[j] = f2bf(y); l1[j] = f2bf(y - bf2f(h1[j]));
        }
        *(ushort8*)(W2thi + (size_t)n * HID_CH + kc)     = h0;
        *(ushort8*)(W2thi + (size_t)n * HID_CH + kc + 8) = h1;
        *(ushort8*)(W2tlo + (size_t)n * HID_CH + kc)     = l0;
        *(ushort8*)(W2tlo + (size_t)n * HID_CH + kc + 8) = l1;
    }
    // slot-CSR build: deg count + bucket fill (no scan)
    for (int i = g; i < N_EDGES; i += gsz) {
        int c = col[i];
        int r = row[i];
        int p = atomicAdd(&deg[c], 1);
        srcs[(size_t)c * CAP + p] = (unsigned short)r;
    }
}

// ---------------------------------------------------------------------------
// split-bf16 MFMA GEMM, epilogue scales by dinv[m] = rsqrt(deg[m]+1), fp16 out.
// AMODE 1: A fp32 [M][K]; AMODE 2: A fp16 [M][K]. Either way A is split to
// bf16 hi/lo in-register while staging (fp16->bf16x2 is exact).
// TM x 128 tile, BK=32, 4 waves (2x2), (TM/32)x4 16x16x32 MFMA tiles/wave.
// 3-term compensation: hi*hi + hi*lo + lo*hi.
// ---------------------------------------------------------------------------
#define GK 256
template <int AMODE, int TM>
__global__ __launch_bounds__(256)
void gemm_mfma_kernel(const float* __restrict__ Afp, const _Float16* __restrict__ Ah,
                      const unsigned short* __restrict__ Bthi, const unsigned short* __restrict__ Btlo,
                      const int* __restrict__ deg, _Float16* __restrict__ C, int M, int N) {
    constexpr int MI = TM / 32;
    __shared__ unsigned short As[2][TM][36];
    __shared__ unsigned short Bs[2][128][36];
    const int tid = threadIdx.x;
    const int m0 = blockIdx.y * TM;
    const int n0 = blockIdx.x * 128;
    const int lane = tid & 63;
    const int wave = tid >> 6;
    const int wr = (wave >> 1) * (TM / 2);
    const int wc = (wave & 1) * 64;
    const int lm = lane & 15;
    const int lk = (lane >> 4) * 8;

    floatx4 acc[MI][4];
#pragma unroll
    for (int i = 0; i < MI; ++i)
#pragma unroll
        for (int j = 0; j < 4; ++j) acc[i][j] = (floatx4){0.f, 0.f, 0.f, 0.f};

    for (int k0 = 0; k0 < GK; k0 += 32) {
#pragma unroll
        for (int c = 0; c < TM / 64; ++c) {
            int ch = tid + c * 256;
            int r = ch >> 2;
            int ko = (ch & 3) * 8;
            ushort8 vh = {}, vl = {};
            if (m0 + r < M) {
                float xs[8];
                if (AMODE == 1) {
                    const float* ap = Afp + (size_t)(m0 + r) * GK + k0 + ko;
                    float4 f0 = *(const float4*)ap;
                    float4 f1 = *(const float4*)(ap + 4);
                    xs[0] = f0.x; xs[1] = f0.y; xs[2] = f0.z; xs[3] = f0.w;
                    xs[4] = f1.x; xs[5] = f1.y; xs[6] = f1.z; xs[7] = f1.w;
                } else {
                    half8 hv = *(const half8*)(Ah + (size_t)(m0 + r) * GK + k0 + ko);
#pragma unroll
                    for (int j = 0; j < 8; ++j) xs[j] = (float)hv[j];
                }
#pragma unroll
                for (int j = 0; j < 8; ++j) {
                    vh[j] = f2bf(xs[j]);
                    vl[j] = f2bf(xs[j] - bf2f(vh[j]));
                }
            }
            *(ushort8*)&As[0][r][ko] = vh;
            *(ushort8*)&As[1][r][ko] = vl;
        }
#pragma unroll
        for (int c = 0; c < 2; ++c) {
            int ch = tid + c * 256;
            int r = ch >> 2;
            int ko = (ch & 3) * 8;
            size_t gb = (size_t)(n0 + r) * GK + k0 + ko;
            *(ushort8*)&Bs[0][r][ko] = *(const ushort8*)(Bthi + gb);
            *(ushort8*)&Bs[1][r][ko] = *(const ushort8*)(Btlo + gb);
        }
        __syncthreads();

        short8 ah[MI], al[MI], bh[4], bl[4];
#pragma unroll
        for (int i = 0; i < MI; ++i) {
            ah[i] = *(const short8*)&As[0][wr + i * 16 + lm][lk];
            al[i] = *(const short8*)&As[1][wr + i * 16 + lm][lk];
        }
#pragma unroll
        for (int j = 0; j < 4; ++j) {
            bh[j] = *(const short8*)&Bs[0][wc + j * 16 + lm][lk];
            bl[j] = *(const short8*)&Bs[1][wc + j * 16 + lm][lk];
        }
#pragma unroll
        for (int i = 0; i < MI; ++i)
#pragma unroll
            for (int j = 0; j < 4; ++j) {
                acc[i][j] = __builtin_amdgcn_mfma_f32_16x16x32_bf16(ah[i], bh[j], acc[i][j], 0, 0, 0);
                acc[i][j] = __builtin_amdgcn_mfma_f32_16x16x32_bf16(ah[i], bl[j], acc[i][j], 0, 0, 0);
                acc[i][j] = __builtin_amdgcn_mfma_f32_16x16x32_bf16(al[i], bh[j], acc[i][j], 0, 0, 0);
            }
        __syncthreads();
    }

#pragma unroll
    for (int i = 0; i < MI; ++i) {
#pragma unroll
        for (int r = 0; r < 4; ++r) {
            int rowi = m0 + wr + i * 16 + (lane >> 4) * 4 + r;
            if (rowi < M) {
                float dr = 1.0f / sqrtf((float)(deg[rowi] + 1));
#pragma unroll
                for (int j = 0; j < 4; ++j) {
                    C[(size_t)rowi * N + n0 + wc + j * 16 + lm] = (_Float16)(dr * acc[i][j][r]);
                }
            }
        }
    }
}

// ---------------------------------------------------------------------------
// XCD-sliced gather over ushort slot-CSR, fp16 X table. Slice = 32 ch;
// 16 lanes per node (half2/lane) -> 4 node-groups/wave (divergence: max of 4
// Poisson(16) instead of 8). One edge row-slice = 64 B contiguous.
// X rows dinv[src]-prescaled by GEMM epilogue.
// MODE 0: fp32 NT store to final out. MODE 1: relu + fp16 H1 (cached).
// ---------------------------------------------------------------------------
template <int C, int NSLICE, int MODE>
__global__ __launch_bounds__(256)
void gather_sliced_kernel(const _Float16* __restrict__ X, const int* __restrict__ deg,
                          const unsigned short* __restrict__ srcs,
                          const float* __restrict__ bias, float* __restrict__ outf,
                          _Float16* __restrict__ outh, int n) {
    constexpr int SW = C / NSLICE;
    static_assert(SW == 32, "slice must be 32 channels");
    const int slice = blockIdx.x % NSLICE;
    const int ngrp  = blockIdx.x / NSLICE;
    const int wave = threadIdx.x >> 6;
    const int lane = threadIdx.x & 63;
    const int g  = lane >> 4;          // node sub-group 0..3
    const int sl = lane & 15;          // sublane: 2 channels each
    const int node = ngrp * 16 + wave * 4 + g;
    if (node >= n) return;
    const int choff = slice * SW + sl * 2;
    const size_t beg = (size_t)node * CAP;
    const int cnt = deg[node];

    float a0 = 0.f, a1 = 0.f;
    int e = 0;
    for (; e + 4 <= cnt; e += 4) {
        ushort4v s4 = *(const ushort4v*)(srcs + beg + e);
        half2v v0 = *(const half2v*)(X + (size_t)s4.x * C + choff);
        half2v v1 = *(const half2v*)(X + (size_t)s4.y * C + choff);
        half2v v2 = *(const half2v*)(X + (size_t)s4.z * C + choff);
        half2v v3 = *(const half2v*)(X + (size_t)s4.w * C + choff);
        a0 += (float)v0.x + (float)v1.x + (float)v2.x + (float)v3.x;
        a1 += (float)v0.y + (float)v1.y + (float)v2.y + (float)v3.y;
    }
    for (; e < cnt; ++e) {
        int r = srcs[beg + e];
        half2v v = *(const half2v*)(X + (size_t)r * C + choff);
        a0 += (float)v.x; a1 += (float)v.y;
    }

    const float dc = 1.0f / sqrtf((float)(cnt + 1));
    half2v vsh = *(const half2v*)(X + (size_t)node * C + choff);  // dinv[node]-prescaled
    float2 bb = *(const float2*)(bias + choff);

    float o0 = dc * (a0 + (float)vsh.x) + bb.x;
    float o1 = dc * (a1 + (float)vsh.y) + bb.y;

    if constexpr (MODE == 1) {
        half2v h;
        h.x = (_Float16)fmaxf(o0, 0.f);
        h.y = (_Float16)fmaxf(o1, 0.f);
        *(half2v*)(outh + (size_t)node * C + choff) = h;   // cached: gemm2 reads next
    } else {
        floatx2 o = {o0, o1};
        __builtin_nontemporal_store(o, (floatx2*)(outf + (size_t)node * C + choff));
    }
}

// ---------------------------------------------------------------------------
extern "C" void kernel_launch(void* const* d_in, const int* in_sizes, int n_in,
                              void* d_out, int out_size, void* d_ws, size_t ws_size,
                              hipStream_t stream) {
    const float* doc_embeds = (const float*)d_in[0];   // [20000,256]
    const int*   edge_index = (const int*)d_in[1];     // [2,320000]
    const float* W1 = (const float*)d_in[2];           // [256,256]
    const float* b1 = (const float*)d_in[3];           // [256]
    const float* W2 = (const float*)d_in[4];           // [256,128]
    const float* b2 = (const float*)d_in[5];           // [128]
    float* out = (float*)d_out;                        // [20000,128]

    const int* row = edge_index;            // sources
    const int* col = edge_index + N_EDGES;  // destinations

    // ---------------- workspace layout (256B aligned) ----------------
    char* ws = (char*)d_ws;
    auto align_up = [](size_t x) { return (x + 255) / 256 * 256; };

    _Float16* X1s = (_Float16*)(ws);                              // gemm1 out fp16 (10.24 MB)
    _Float16* H1  = (_Float16*)(ws + align_up((size_t)N_NODES * HID_CH * 2));  // fp16 (10.24 MB)
    _Float16* X2s = X1s;                                          // gemm2 out reuses X1s (5.12 MB)
    char* meta = (char*)(ws + 2 * align_up((size_t)N_NODES * HID_CH * 2));
    unsigned short* W1thi = (unsigned short*)(meta); meta += align_up((size_t)IN_CH * HID_CH * 2);
    unsigned short* W1tlo = (unsigned short*)(meta); meta += align_up((size_t)IN_CH * HID_CH * 2);
    unsigned short* W2thi = (unsigned short*)(meta); meta += align_up((size_t)HID_CH * OUT_CH * 2);
    unsigned short* W2tlo = (unsigned short*)(meta); meta += align_up((size_t)HID_CH * OUT_CH * 2);
    int*            deg   = (int*)(meta);            meta += align_up((size_t)N_NODES * 4);
    unsigned short* srcs  = (unsigned short*)(meta); // 20000*64*2 = 2.56 MB

    // ---------------- prep: zero deg (memset), fused weights + slot-CSR ----------------
    hipMemsetAsync(deg, 0, (size_t)N_NODES * 4, stream);
    prep_kernel<<<(N_EDGES + 255) / 256, 256, 0, stream>>>(
        W1, W2, W1thi, W1tlo, W2thi, W2tlo, row, col, deg, srcs);

    // ---------------- layer 1 ----------------
    {
        dim3 grid(HID_CH / 128, (N_NODES + 63) / 64);   // (2, 313)
        gemm_mfma_kernel<1, 64><<<grid, 256, 0, stream>>>(
            doc_embeds, nullptr, W1thi, W1tlo, deg, X1s, N_NODES, HID_CH);
    }
    gather_sliced_kernel<HID_CH, 8, 1><<<((N_NODES + 15) / 16) * 8, 256, 0, stream>>>(
        X1s, deg, srcs, b1, nullptr, H1, N_NODES);

    // ---------------- layer 2 ----------------
    {
        dim3 grid(OUT_CH / 128, (N_NODES + 63) / 64);   // (1, 313)
        gemm_mfma_kernel<2, 64><<<grid, 256, 0, stream>>>(
            nullptr, H1, W2thi, W2tlo, deg, X2s, N_NODES, OUT_CH);
    }
    gather_sliced_kernel<OUT_CH, 4, 0><<<((N_NODES + 15) / 16) * 4, 256, 0, stream>>>(
        X2s, deg, srcs, b2, out, nullptr, N_NODES);
}